// Round 1
// 86.565 us; speedup vs baseline: 1.0126x; 1.0126x over previous
//
#include <hip/hip_runtime.h>
#include <math.h>

// AFM via Gram MFMA (16x16x32 f16), R8: spill-hypothesis probe.
//   t_k = X diag(W[:,k]) X^T ; logit = sum_k relu(t_k+b_k) h_k
//   out = (sum_{i<j} exp(logit) s_ij)/(sum exp(logit)), s = X diag(p) X^T
// R8 vs R7:
//  - __launch_bounds__(NT,4) -> (NT,2): R7's live set (fr 32 + lg 20 + t 20
//    + sa + pa 32 + addr) likely exceeds the 128-VGPR cap that (.,4) imposes
//    -> scratch spills in the k-loop. Lift the cap; worst case occupancy
//    4->3 blocks/CU on a VALU-bound kernel.
//  - PW=1 now scales the B operand (unique TJ = {2,3}, 2 sets) instead of
//    A (unique TI = {1,2,3}, 3 sets): Gram symmetry X diag(w) X^T allows
//    scaling either side; saves 4 pk_mul x 2es x 11k per PW=1 wave.
// Gram symmetry: one 8-fragment set (32 VGPR) serves both MFMA operands.

#define F_ 50
#define E_ 64
#define A_ 10
#define NT 256           // 4 waves: 2 batches x 2 waves
#define LOG2E 1.44269504088896f

typedef _Float16 half8 __attribute__((ext_vector_type(8)));
typedef _Float16 half4t __attribute__((ext_vector_type(4)));
typedef float f32x4 __attribute__((ext_vector_type(4)));

// PW=0: tiles (0,0),(0,1),(0,2),(0,3),(1,1)
// PW=1: tiles (1,2),(1,3),(2,2),(2,3),(3,3)
template <int PW>
__device__ __forceinline__ void compute_half(const float* __restrict__ xg,
                                             const _Float16* __restrict__ sWh,
                                             const float* __restrict__ sb,
                                             const float* __restrict__ sh,
                                             int lane, float& num, float& den) {
  constexpr int TI[5] = { PW ? 1 : 0, PW ? 1 : 0, PW ? 2 : 0, PW ? 2 : 0, PW ? 3 : 1 };
  constexpr int TJ[5] = { PW ? 2 : 0, PW ? 3 : 1, PW ? 2 : 2, PW ? 3 : 3, PW ? 3 : 1 };
  // Scale the operand side with fewer unique tile indices:
  //   PW=0: A-side, unique TI = {0,1}; PW=1: B-side, unique TJ = {2,3}.
  constexpr bool SCALE_A = (PW == 0);
  constexpr bool NEED[4] = { PW == 0, PW == 0, PW != 0, PW != 0 };

  const int m = lane & 15, q8 = lane >> 4;

  // ---- fragments direct from global fp32, cvt to fp16 in regs ----
  // A[m][k]: m=lane&15, k=(lane>>4)*8+j — identical addressing for A and B.
  half8 fr[4][2];
#pragma unroll
  for (int bi = 0; bi < 4; ++bi) {
    const int row = bi * 16 + m;
    const bool rv = (bi < 3) || (m < F_ - 48);   // row < 50
#pragma unroll
    for (int es = 0; es < 2; ++es) {
      float4 v0 = { 0.f, 0.f, 0.f, 0.f }, v1 = v0;
      if (rv) {
        const float* p = xg + row * E_ + es * 32 + q8 * 8;
        v0 = *(const float4*)p;
        v1 = *(const float4*)(p + 4);
      }
      half8 hv = { (_Float16)v0.x, (_Float16)v0.y, (_Float16)v0.z, (_Float16)v0.w,
                   (_Float16)v1.x, (_Float16)v1.y, (_Float16)v1.z, (_Float16)v1.w };
      fr[bi][es] = hv;
    }
  }

  float lg[5][4];
#pragma unroll
  for (int tt = 0; tt < 5; ++tt)
#pragma unroll
    for (int r = 0; r < 4; ++r) lg[tt][r] = 0.f;

#pragma unroll 1
  for (int k = 0; k < A_; ++k) {
    half8 wv0 = *(const half8*)(sWh + k * E_ + q8 * 8);       // broadcast
    half8 wv1 = *(const half8*)(sWh + k * E_ + 32 + q8 * 8);
    float bk = sb[k];
    f32x4 ci = { bk, bk, bk, bk };
    half8 sc[4];
#pragma unroll
    for (int bi = 0; bi < 4; ++bi)
      if (NEED[bi]) sc[bi] = fr[bi][0] * wv0;                 // pk_mul
    f32x4 t[5];
#pragma unroll
    for (int tt = 0; tt < 5; ++tt)
      t[tt] = __builtin_amdgcn_mfma_f32_16x16x32_f16(
          SCALE_A ? sc[TI[tt]] : fr[TI[tt]][0],
          SCALE_A ? fr[TJ[tt]][0] : sc[TJ[tt]], ci, 0, 0, 0);
#pragma unroll
    for (int bi = 0; bi < 4; ++bi)
      if (NEED[bi]) sc[bi] = fr[bi][1] * wv1;
#pragma unroll
    for (int tt = 0; tt < 5; ++tt)
      t[tt] = __builtin_amdgcn_mfma_f32_16x16x32_f16(
          SCALE_A ? sc[TI[tt]] : fr[TI[tt]][1],
          SCALE_A ? fr[TJ[tt]][1] : sc[TJ[tt]], t[tt], 0, 0, 0);
    float hk = sh[k];   // pre-scaled by log2(e)
#pragma unroll
    for (int tt = 0; tt < 5; ++tt)
#pragma unroll
      for (int r = 0; r < 4; ++r)
        lg[tt][r] = fmaf(fmaxf(t[tt][r], 0.f), hk, lg[tt][r]);
  }

  // ---- proj Gram + masked exp fold ----
  half8 pv0 = *(const half8*)(sWh + A_ * E_ + q8 * 8);
  half8 pv1 = *(const half8*)(sWh + A_ * E_ + 32 + q8 * 8);
  half8 pc0[4], pc1[4];
#pragma unroll
  for (int bi = 0; bi < 4; ++bi)
    if (NEED[bi]) { pc0[bi] = fr[bi][0] * pv0; pc1[bi] = fr[bi][1] * pv1; }
  f32x4 z4 = { 0.f, 0.f, 0.f, 0.f };
#pragma unroll
  for (int tt = 0; tt < 5; ++tt) {
    f32x4 s4 = __builtin_amdgcn_mfma_f32_16x16x32_f16(
        SCALE_A ? pc0[TI[tt]] : fr[TI[tt]][0],
        SCALE_A ? fr[TJ[tt]][0] : pc0[TJ[tt]], z4, 0, 0, 0);
    s4 = __builtin_amdgcn_mfma_f32_16x16x32_f16(
        SCALE_A ? pc1[TI[tt]] : fr[TI[tt]][1],
        SCALE_A ? fr[TJ[tt]][1] : pc1[TJ[tt]], s4, 0, 0, 0);
#pragma unroll
    for (int r = 0; r < 4; ++r) {
      int irow = TI[tt] * 16 + q8 * 4 + r;   // C/D: row=(lane>>4)*4+reg
      int jcol = TJ[tt] * 16 + m;            //      col=lane&15
      bool valid = (irow < jcol) && (jcol < F_);
      float w = valid ? exp2f(lg[tt][r]) : 0.f;
      num = fmaf(w, s4[r], num);
      den += w;
    }
  }
}

__global__ __launch_bounds__(NT, 2)
void afm_kernel(const float* __restrict__ x,
                const float* __restrict__ W,
                const float* __restrict__ bias,
                const float* __restrict__ h,
                const float* __restrict__ pp,
                float* __restrict__ out, int nbatch) {
  __shared__ __align__(16) _Float16 sWh[(A_ + 1) * E_];   // k<10: W[:,k]; 10: p
  __shared__ float sb[A_], sh[A_];
  __shared__ float rn[4], rd[4];

  const int tid = threadIdx.x;
  const int lane = tid & 63, w4 = tid >> 6;
  const int pair = tid >> 7;                 // 2 waves per batch
  const int b = blockIdx.x * 2 + pair;
  const bool bvalid = b < nbatch;

  // ---- stage W (e-major -> k-major fp16) + p as row 10; tiny, one barrier ----
  if (tid < 11 * 16) {
    int k = tid >> 4, e4 = tid & 15;
    float v0, v1, v2, v3;
    if (k < A_) {
      v0 = W[(e4 * 4 + 0) * A_ + k]; v1 = W[(e4 * 4 + 1) * A_ + k];
      v2 = W[(e4 * 4 + 2) * A_ + k]; v3 = W[(e4 * 4 + 3) * A_ + k];
    } else {
      float4 t4 = *(const float4*)(pp + e4 * 4);
      v0 = t4.x; v1 = t4.y; v2 = t4.z; v3 = t4.w;
    }
    half4t hv = { (_Float16)v0, (_Float16)v1, (_Float16)v2, (_Float16)v3 };
    *(half4t*)(sWh + k * E_ + e4 * 4) = hv;
  }
  if (tid < A_) { sb[tid] = bias[tid]; sh[tid] = h[tid] * LOG2E; }
  __syncthreads();

  float num = 0.f, den = 0.f;
  if (bvalid) {
    const float* xg = x + (size_t)b * (F_ * E_);
    if ((w4 & 1) == 0) compute_half<0>(xg, sWh, sb, sh, lane, num, den);
    else               compute_half<1>(xg, sWh, sb, sh, lane, num, den);
  }

  // ---- reduce: wave shuffle -> LDS -> combine the 2 waves of each batch ----
#pragma unroll
  for (int off = 32; off; off >>= 1) {
    num += __shfl_down(num, off);
    den += __shfl_down(den, off);
  }
  if (lane == 0) { rn[w4] = num; rd[w4] = den; }
  __syncthreads();
  if ((tid == 0 || tid == 128) && bvalid)
    out[b] = (rn[pair * 2] + rn[pair * 2 + 1]) / (rd[pair * 2] + rd[pair * 2 + 1]);
}

extern "C" void kernel_launch(void* const* d_in, const int* in_sizes, int n_in,
                              void* d_out, int out_size, void* d_ws, size_t ws_size,
                              hipStream_t stream) {
  const float* x  = (const float*)d_in[0];
  const float* W  = (const float*)d_in[1];
  const float* bb = (const float*)d_in[2];
  const float* h  = (const float*)d_in[3];
  const float* pp = (const float*)d_in[4];
  float* out = (float*)d_out;
  const int nbatch = in_sizes[0] / (F_ * E_);
  const int nblocks = (nbatch + 1) / 2;
  afm_kernel<<<nblocks, NT, 0, stream>>>(x, W, bb, h, pp, out, nbatch);
}